// Round 10
// baseline (255.267 us; speedup 1.0000x reference)
//
#include <hip/hip_runtime.h>

// Problem constants (fixed by reference: B=4, C=512, H=W=64, MID=64)
#define BB 4
#define CD 512
#define NP 4096
#define MID 64

typedef _Float16 half8 __attribute__((ext_vector_type(8)));
typedef _Float16 half4 __attribute__((ext_vector_type(4)));
typedef float floatx4 __attribute__((ext_vector_type(4)));

#define LOG2E 1.4426950408889634f

// ---------------------------------------------------------------------------
// Kernel 1: pack wq|wk|wv -> fp16 [640][512], concat biases (fp32 [640]).
// ---------------------------------------------------------------------------
__global__ __launch_bounds__(256) void prep_w(
    const float* __restrict__ wq, const float* __restrict__ wk,
    const float* __restrict__ wv, const float* __restrict__ bq,
    const float* __restrict__ bk, const float* __restrict__ bv,
    _Float16* __restrict__ w_h, float* __restrict__ bias) {
  int idx = blockIdx.x * 256 + threadIdx.x;
  for (int i = idx; i < 640 * 512; i += gridDim.x * 256) {
    int r = i >> 9, c = i & 511;
    float v = (r < 64) ? wq[(r << 9) + c] * LOG2E
            : (r < 128) ? wk[((r - 64) << 9) + c]
                        : wv[((r - 128) << 9) + c];
    w_h[i] = (_Float16)v;
  }
  if (idx < 640) {
    float v = (idx < 64) ? bq[idx] * LOG2E
            : (idx < 128) ? bk[idx - 64]
                          : bv[idx - 128];
    bias[idx] = v;
  }
}

// ---------------------------------------------------------------------------
// Kernel 2: transpose x [b][c][n] fp32 -> xt [b][n][c] fp16 (64x64 LDS tiles)
// ---------------------------------------------------------------------------
__global__ __launch_bounds__(256) void transpose_x(const float* __restrict__ x,
                                                   _Float16* __restrict__ xt) {
  __shared__ float tile[64][65];
  int b = blockIdx.z, c0 = blockIdx.y * 64, n0 = blockIdx.x * 64;
  int t = threadIdx.x;
  const float* xb = x + (size_t)b * CD * NP;
#pragma unroll
  for (int k = 0; k < 16; k++) {
    int cl = k * 4 + (t >> 6);
    int nl = t & 63;
    tile[cl][nl] = xb[(size_t)(c0 + cl) * NP + n0 + nl];
  }
  __syncthreads();
  _Float16* xtb = xt + ((size_t)b * NP + n0) * CD + c0;
#pragma unroll
  for (int k = 0; k < 2; k++) {
    int nl = k * 32 + (t >> 3);
    int cl = (t & 7) * 8;
    half8 pk;
#pragma unroll
    for (int i = 0; i < 8; i++) pk[i] = (_Float16)tile[cl + i][nl];
    *(half8*)(xtb + (size_t)nl * CD + cl) = pk;
  }
}

// ---------------------------------------------------------------------------
// Kernel 3: fused QKV projection (unchanged).
// ---------------------------------------------------------------------------
__global__ __launch_bounds__(256, 2) void proj_qkv(
    const _Float16* __restrict__ w_h, const float* __restrict__ bias,
    const _Float16* __restrict__ xt, _Float16* __restrict__ q_h,
    _Float16* __restrict__ k_h, _Float16* __restrict__ v_h) {
  __shared__ _Float16 xls[64 * 512];   // 64 KB, XOR-swizzled 16B units
  int t = threadIdx.x, w = t >> 6, lane = t & 63;
  int col = lane & 15, quad = lane >> 4;
  int rbh = blockIdx.x, nb = blockIdx.y, b = blockIdx.z;
  int n0 = nb * 64;
  const _Float16* xtb = xt + ((size_t)b * NP + n0) * CD;
#pragma unroll
  for (int j = 0; j < 16; j++) {
    int u = t + j * 256;
    int row = u >> 6, un = u & 63;
    *(half8*)(xls + row * 512 + ((un ^ (row & 7)) << 3)) =
        *(const half8*)(xtb + (size_t)row * CD + un * 8);
  }
  __syncthreads();

  int rw = rbh * 320 + w * 80;
  floatx4 acc[5][4] = {};
  for (int c = 0; c < CD; c += 32) {
    int cu = c >> 3;
    half8 a[5], bf[4];
#pragma unroll
    for (int i = 0; i < 5; i++)
      a[i] = *(const half8*)(w_h + (size_t)(rw + i * 16 + col) * CD + c + quad * 8);
#pragma unroll
    for (int j = 0; j < 4; j++) {
      int row = j * 16 + col;
      bf[j] = *(const half8*)(xls + row * 512 + (((cu + quad) ^ (row & 7)) << 3));
    }
#pragma unroll
    for (int i = 0; i < 5; i++)
#pragma unroll
      for (int j = 0; j < 4; j++)
        acc[i][j] = __builtin_amdgcn_mfma_f32_16x16x32_f16(a[i], bf[j], acc[i][j], 0, 0, 0);
  }

#pragma unroll
  for (int i = 0; i < 5; i++) {
    int r0 = rw + i * 16;
    float bi[4];
#pragma unroll
    for (int rr = 0; rr < 4; rr++) bi[rr] = bias[r0 + quad * 4 + rr];
    if (r0 < 128) {
      _Float16* dst = (r0 < 64 ? q_h + (size_t)b * NP * MID + r0
                               : k_h + (size_t)b * NP * MID + (r0 - 64));
#pragma unroll
      for (int j = 0; j < 4; j++) {
        int n = n0 + j * 16 + col;
        half4 pk;
#pragma unroll
        for (int rr = 0; rr < 4; rr++) pk[rr] = (_Float16)(acc[i][j][rr] + bi[rr]);
        *(half4*)(dst + (size_t)n * MID + quad * 4) = pk;
      }
    } else {
      int dbase = r0 - 128 + quad * 4;
#pragma unroll
      for (int j = 0; j < 4; j++) {
        int n = n0 + j * 16 + col;
#pragma unroll
        for (int rr = 0; rr < 4; rr++)
          v_h[((size_t)b * CD + dbase + rr) * NP + n] =
              (_Float16)(acc[i][j][rr] + bi[rr]);
      }
    }
  }
}

// ---------------------------------------------------------------------------
// Kernel 4: row max of S (unchanged).
// ---------------------------------------------------------------------------
__global__ __launch_bounds__(256) void rowmax(const _Float16* __restrict__ q_h,
                                              const _Float16* __restrict__ k_h,
                                              float* __restrict__ M) {
  int qb = blockIdx.x, b = blockIdx.y;
  int t = threadIdx.x, w = t >> 6, lane = t & 63;
  int col = lane & 15, quad = lane >> 4;
  int q0 = qb * 32;
  const _Float16* qp = q_h + ((size_t)b * NP + q0) * MID;
  half8 bq[2][2];
#pragma unroll
  for (int qt = 0; qt < 2; qt++)
#pragma unroll
    for (int h = 0; h < 2; h++)
      bq[qt][h] = *(const half8*)(qp + (size_t)(qt * 16 + col) * MID + h * 32 + quad * 8);
  const _Float16* kp = k_h + ((size_t)b * NP + (size_t)w * 1024) * MID;
  float m[2] = {-1e30f, -1e30f};
#pragma unroll 4
  for (int n = 0; n < 1024; n += 16) {
    half8 ak0 = *(const half8*)(kp + (size_t)(n + col) * MID + quad * 8);
    half8 ak1 = *(const half8*)(kp + (size_t)(n + col) * MID + 32 + quad * 8);
#pragma unroll
    for (int qt = 0; qt < 2; qt++) {
      floatx4 s = {};
      s = __builtin_amdgcn_mfma_f32_16x16x32_f16(ak0, bq[qt][0], s, 0, 0, 0);
      s = __builtin_amdgcn_mfma_f32_16x16x32_f16(ak1, bq[qt][1], s, 0, 0, 0);
      m[qt] = fmaxf(m[qt], fmaxf(fmaxf(s[0], s[1]), fmaxf(s[2], s[3])));
    }
  }
  __shared__ float red[4][2][16];
#pragma unroll
  for (int qt = 0; qt < 2; qt++) {
    m[qt] = fmaxf(m[qt], __shfl_xor(m[qt], 16));
    m[qt] = fmaxf(m[qt], __shfl_xor(m[qt], 32));
  }
  if (quad == 0) {
    red[w][0][col] = m[0];
    red[w][1][col] = m[1];
  }
  __syncthreads();
  if (t < 32) {
    int qt = t >> 4, c = t & 15;
    float mm = fmaxf(fmaxf(red[0][qt][c], red[1][qt][c]),
                     fmaxf(red[2][qt][c], red[3][qt][c]));
    M[(size_t)b * NP + q0 + t] = mm;
  }
}

// ---------------------------------------------------------------------------
// Kernel 5: attention + PV + epilogue, v13 (order-independent DMA gates).
// Grid 512 = b(4) x ds(2) x qb(64); block = 4 waves = 64q x 256d.
// v12b race post-mortem: lgkmcnt(15)/(4) gates assumed a specific ds_read
// ISSUE ORDER, but the compiler orders the 18 reads freely -> the K/V
// refill DMAs could overwrite LDS under in-flight reads (nondeterministic
// fail). v13: ONE lgkmcnt(0) after the P-writes (retires ALL reads
// regardless of order -- near-free: reads were issued a full score-phase
// earlier, and the P-writes had to drain before the barrier anyway), THEN
// both refill DMAs (K(ci+1) x2, V(ci) x8), THEN the PV cluster. DMAs fly
// across PV + barrier to the next body's vmcnt(0).
// Conflict-free swizzles kept from v12: V source-swizzle u^((r>>1)&3),
// P unit-swizzle u^(row bit2), K u^(key&7).
// LDS 58624B: vbuf 2x16K (h-index) | kbuf 8K | pbuf 2x8K | lred/lfin 1.25K.
// ---------------------------------------------------------------------------
#define DMA16(gp, ldsoff)                                                      \
  asm volatile("s_mov_b32 m0, %0\n\t"                                         \
               "global_load_lds_dwordx4 %1, off"                              \
               :: "s"(__builtin_amdgcn_readfirstlane((int)(ldsoff))),          \
                  "v"(gp)                                                      \
               : "memory")

__global__ __launch_bounds__(256, 2) void attn_pv(
    const _Float16* __restrict__ q_h, const _Float16* __restrict__ k_h,
    const _Float16* __restrict__ v_h, const float* __restrict__ M,
    const float* __restrict__ x, const float* __restrict__ alpha_p,
    float* __restrict__ out) {
  int bid = blockIdx.x;
  int combo = bid & 7;               // -> XCD via round-robin dispatch
  int b = combo >> 1, ds = combo & 1;
  int qb = bid >> 3;                 // 0..63
  int q0 = qb * 64, d0 = ds * 256;

  int t = threadIdx.x, w = t >> 6, lane = t & 63;
  int col = lane & 15, quad = lane >> 4;
  int c7 = col & 7;

  __shared__ floatx4 smem4[58624 / 16];
  char* smem = (char*)smem4;
  char* vbufB = smem;                    // 2 x 16384 (h-indexed)
  char* kbufB = smem + 32768;            // 8192 (single buffer)
  char* pbufB = smem + 40960;            // 2 x 8192 (chunk parity)
  float* lred = (float*)(smem + 57344);  // [4][4][16]
  float* lfin = (float*)(smem + 58368);  // [64]

  const _Float16* qp = q_h + ((size_t)b * NP + q0) * MID;
  half8 bq[4][2];
#pragma unroll
  for (int qt = 0; qt < 4; qt++)
#pragma unroll
    for (int h = 0; h < 2; h++)
      bq[qt][h] = *(const half8*)(qp + (size_t)(qt * 16 + col) * MID + h * 32 + quad * 8);
  float Mq[4];
#pragma unroll
  for (int qt = 0; qt < 4; qt++) Mq[qt] = M[(size_t)b * NP + q0 + qt * 16 + col];

  // DMA source offsets (involution swizzles, constant across chunks):
  // K: slot(key=lane>>3, u=lane&7) holds logical d-unit u^(key&7)
  int klane = (lane >> 3) * MID + (((lane & 7) ^ ((lane >> 3) & 7)) << 3);
  // V: slot(d-row r=lane>>2, u=lane&3) holds logical k-unit u^((r>>1)&3)
  size_t vlane = (size_t)(lane >> 2) * NP + (((lane & 3) ^ ((lane >> 3) & 3)) << 3);

  const _Float16* kgb = k_h + (size_t)b * NP * MID;
  const _Float16* vgb = v_h + (size_t)(b * CD + d0 + w * 64) * NP;

  floatx4 acc[4][4] = {};            // [dt][qt] = 64 VGPRs, static indices
  float lp[4] = {0.f, 0.f, 0.f, 0.f};

  int kdw = 32768 + w * 2048;        // kbuf wave base (LDS bytes)
  int vdw = w * 4096;                // vbuf wave base

  // read byte-offsets
  int koff0 = col * 128 + ((quad ^ c7) << 4);           // K logical unit quad
  int koff1 = col * 128 + (((quad ^ c7) ^ 4) << 4);     // K logical unit 4+quad
  int vswz = (quad ^ ((col >> 1) & 3)) << 4;            // V swizzled unit
  int pws = ((((quad >> 1) ^ ((col >> 2) & 1)) << 4)) + ((quad & 1) << 3);
  int prs = (((quad & 1) ^ ((col >> 2) & 1)) << 4);

  // ---- prologue DMAs: K(0) x2 then V(0) x8 ----
#pragma unroll
  for (int j = 0; j < 2; j++)
    DMA16(kgb + (size_t)(w * 16 + j * 8) * MID + klane, kdw + j * 1024);
#pragma unroll
  for (int h = 0; h < 2; h++)
#pragma unroll
    for (int j = 0; j < 4; j++)
      DMA16(vgb + (size_t)(j * 16) * NP + h * 32 + vlane,
            h * 16384 + vdw + j * 1024);

  // ---- peeled chunk 0: score only ----
  asm volatile("s_waitcnt vmcnt(8)" ::: "memory");   // K(0) landed (2 oldest)
  {
    const char* kb = kbufB + w * 2048;
    half8 ak0 = *(const half8*)(kb + koff0);
    half8 ak1 = *(const half8*)(kb + koff1);
    char* pbW = pbufB + w * 2048;                    // pbuf[0]
#pragma unroll
    for (int qt = 0; qt < 4; qt++) {
      floatx4 s = {};
      s = __builtin_amdgcn_mfma_f32_16x16x32_f16(ak0, bq[qt][0], s, 0, 0, 0);
      s = __builtin_amdgcn_mfma_f32_16x16x32_f16(ak1, bq[qt][1], s, 0, 0, 0);
      half4 pk;
#pragma unroll
      for (int r = 0; r < 4; r++) {
        float pv = __builtin_amdgcn_exp2f(s[r] - Mq[qt]);
        lp[qt] += pv;
        pk[r] = (_Float16)pv;
      }
      *(half4*)(pbW + (qt * 16 + col) * 32 + pws) = pk;
    }
    // ALL LDS ops retired (order-independent) -> kbuf reusable
    asm volatile("s_waitcnt lgkmcnt(0)" ::: "memory");
#pragma unroll
    for (int j = 0; j < 2; j++)
      DMA16(kgb + (size_t)(64 + w * 16 + j * 8) * MID + klane, kdw + j * 1024);
    asm volatile("s_barrier" ::: "memory");          // P(0) published
  }

  // ---- main loop: body ci does score(ci) + PV(ci-1) ----
  for (int ci = 1; ci < 64; ci++) {
    int p = ci & 1;
    int nc = ci * 64;
    int nxt = ((ci + 1) & 63) * 64;

    // K(ci) and V(ci-1) DMAs (issued last body) have ~1-chunk flight.
    asm volatile("s_waitcnt vmcnt(0)" ::: "memory");

    // batch ALL ds reads: K(ci), P(ci-1), V(ci-1)
    const char* kb = kbufB + w * 2048;
    half8 ak0 = *(const half8*)(kb + koff0);
    half8 ak1 = *(const half8*)(kb + koff1);
    const char* pbR = pbufB + (1 - p) * 8192;   // P(ci-1)
    half8 bp[2][4];
#pragma unroll
    for (int h = 0; h < 2; h++)
#pragma unroll
      for (int qt = 0; qt < 4; qt++)
        bp[h][qt] = *(const half8*)(pbR + (2 * h + (quad >> 1)) * 2048 +
                                    (qt * 16 + col) * 32 + prs);
    half8 av[2][4];
#pragma unroll
    for (int h = 0; h < 2; h++)
#pragma unroll
      for (int dt = 0; dt < 4; dt++)
        av[h][dt] = *(const half8*)(vbufB + h * 16384 + vdw + dt * 1024 +
                                    col * 64 + vswz);

    // score(ci)
    floatx4 s[4];
#pragma unroll
    for (int qt = 0; qt < 4; qt++) {
      floatx4 z = {};
      z = __builtin_amdgcn_mfma_f32_16x16x32_f16(ak0, bq[qt][0], z, 0, 0, 0);
      z = __builtin_amdgcn_mfma_f32_16x16x32_f16(ak1, bq[qt][1], z, 0, 0, 0);
      s[qt] = z;
    }

    // exp + P-write(ci) -> pbuf[p]
    char* pbW = pbufB + p * 8192 + w * 2048;
#pragma unroll
    for (int qt = 0; qt < 4; qt++) {
      half4 pk;
#pragma unroll
      for (int r = 0; r < 4; r++) {
        float pv = __builtin_amdgcn_exp2f(s[qt][r] - Mq[qt]);
        lp[qt] += pv;
        pk[r] = (_Float16)pv;
      }
      *(half4*)(pbW + (qt * 16 + col) * 32 + pws) = pk;
    }

    // ONE order-independent gate: ALL reads (and P-writes) retired ->
    // kbuf/vbuf safe to overwrite; PV operands already in VGPRs.
    asm volatile("s_waitcnt lgkmcnt(0)" ::: "memory");
#pragma unroll
    for (int j = 0; j < 2; j++)
      DMA16(kgb + (size_t)(nxt + w * 16 + j * 8) * MID + klane, kdw + j * 1024);
#pragma unroll
    for (int h = 0; h < 2; h++)
#pragma unroll
      for (int j = 0; j < 4; j++)
        DMA16(vgb + (size_t)(j * 16) * NP + nc + h * 32 + vlane,
              h * 16384 + vdw + j * 1024);

    // PV(ci-1): dense 32-MFMA cluster, operands all in regs; DMAs fly over
    __builtin_amdgcn_s_setprio(1);
#pragma unroll
    for (int h = 0; h < 2; h++)
#pragma unroll
      for (int dt = 0; dt < 4; dt++)
#pragma unroll
        for (int qt = 0; qt < 4; qt++)
          acc[dt][qt] = __builtin_amdgcn_mfma_f32_16x16x32_f16(
              av[h][dt], bp[h][qt], acc[dt][qt], 0, 0, 0);
    __builtin_amdgcn_s_setprio(0);

    // ONE barrier per chunk: P(ci) published (lgkm already drained above;
    // this lgkm(0) is a no-op safety net)
    asm volatile("s_waitcnt lgkmcnt(0)\n\ts_barrier" ::: "memory");
  }

  // ---- epilogue: PV(63) ----
  asm volatile("s_waitcnt vmcnt(0)" ::: "memory");   // V(63) landed
  {
    const char* pbR = pbufB + 8192;                  // pbuf[1] = P(63)
    half8 bp[2][4];
#pragma unroll
    for (int h = 0; h < 2; h++)
#pragma unroll
      for (int qt = 0; qt < 4; qt++)
        bp[h][qt] = *(const half8*)(pbR + (2 * h + (quad >> 1)) * 2048 +
                                    (qt * 16 + col) * 32 + prs);
    half8 av[2][4];
#pragma unroll
    for (int h = 0; h < 2; h++)
#pragma unroll
      for (int dt = 0; dt < 4; dt++)
        av[h][dt] = *(const half8*)(vbufB + h * 16384 + vdw + dt * 1024 +
                                    col * 64 + vswz);
#pragma unroll
    for (int h = 0; h < 2; h++)
#pragma unroll
      for (int dt = 0; dt < 4; dt++)
#pragma unroll
        for (int qt = 0; qt < 4; qt++)
          acc[dt][qt] = __builtin_amdgcn_mfma_f32_16x16x32_f16(
              av[h][dt], bp[h][qt], acc[dt][qt], 0, 0, 0);
  }

  // l: lane's partial covers its quad's 4 keys of this wave's sections
#pragma unroll
  for (int qt = 0; qt < 4; qt++) {
    lp[qt] += __shfl_xor(lp[qt], 16);
    lp[qt] += __shfl_xor(lp[qt], 32);
    if (quad == 0) lred[(w * 4 + qt) * 16 + col] = lp[qt];
  }
  __syncthreads();
  if (t < 64) {
    int qt = t >> 4, c = t & 15;
    float l = lred[(0 + qt) * 16 + c] + lred[(4 + qt) * 16 + c] +
              lred[(8 + qt) * 16 + c] + lred[(12 + qt) * 16 + c];
    lfin[t] = alpha_p[0] / l;
  }
  __syncthreads();

  // epilogue: fused alpha/l scale + residual; 64B-segment coalesced stores
  const float* xp = x + ((size_t)(b * CD + d0) + w * 64) * NP;
  float* op = out + ((size_t)(b * CD + d0) + w * 64) * NP;
#pragma unroll
  for (int dt = 0; dt < 4; dt++)
#pragma unroll
    for (int qt = 0; qt < 4; qt++) {
      float linv = lfin[qt * 16 + col];
#pragma unroll
      for (int r = 0; r < 4; r++) {
        size_t o = (size_t)(dt * 16 + quad * 4 + r) * NP + q0 + qt * 16 + col;
        op[o] = acc[dt][qt][r] * linv + xp[o];
      }
    }
}

// ---------------------------------------------------------------------------
extern "C" void kernel_launch(void* const* d_in, const int* in_sizes, int n_in,
                              void* d_out, int out_size, void* d_ws, size_t ws_size,
                              hipStream_t stream) {
  const float* x     = (const float*)d_in[0];
  const float* wq    = (const float*)d_in[1];
  const float* bq    = (const float*)d_in[2];
  const float* wk    = (const float*)d_in[3];
  const float* bk    = (const float*)d_in[4];
  const float* wv    = (const float*)d_in[5];
  const float* bv    = (const float*)d_in[6];
  const float* alpha = (const float*)d_in[7];
  float* out = (float*)d_out;

  char* ws = (char*)d_ws;
  _Float16* w_h  = (_Float16*)(ws);                    // 640*512*2   = 655360
  float*    bias = (float*)(ws + 655360);              // 640*4       = 2560
  float*    Mbuf = (float*)(ws + 657920);              // 4*4096*4    = 65536
  _Float16* xt   = (_Float16*)(ws + 723456);           // 4*4096*512*2= 16777216
  _Float16* q_h  = (_Float16*)(ws + 17500672);         // 4*4096*64*2 = 2097152
  _Float16* k_h  = (_Float16*)(ws + 19597824);         // 4*4096*64*2 = 2097152
  _Float16* v_h  = (_Float16*)(ws + 21694976);         // 4*512*4096*2= 16777216

  prep_w<<<1280, 256, 0, stream>>>(wq, wk, wv, bq, bk, bv, w_h, bias);
  transpose_x<<<dim3(64, 8, BB), 256, 0, stream>>>(x, xt);
  proj_qkv<<<dim3(2, 64, BB), 256, 0, stream>>>(w_h, bias, xt, q_h, k_h, v_h);
  rowmax<<<dim3(128, BB), 256, 0, stream>>>(q_h, k_h, Mbuf);
  attn_pv<<<512, 256, 0, stream>>>(q_h, k_h, v_h, Mbuf, x, alpha, out);
}

// Round 13
// 250.388 us; speedup vs baseline: 1.0195x; 1.0195x over previous
//
#include <hip/hip_runtime.h>

// Problem constants (fixed by reference: B=4, C=512, H=W=64, MID=64)
#define BB 4
#define CD 512
#define NP 4096
#define MID 64

typedef _Float16 half8 __attribute__((ext_vector_type(8)));
typedef _Float16 half4 __attribute__((ext_vector_type(4)));
typedef float floatx4 __attribute__((ext_vector_type(4)));

#define LOG2E 1.4426950408889634f

// ---------------------------------------------------------------------------
// Kernel 1 (merged): blocks 0..2047 transpose x [b][c][n] fp32 -> xt fp16;
// blocks 2048..2175 pack wq|wk|wv -> fp16 [640][512] + biases. One launch
// instead of two (prep_w and transpose_x are independent).
// ---------------------------------------------------------------------------
__global__ __launch_bounds__(256) void prep_trans(
    const float* __restrict__ x, const float* __restrict__ wq,
    const float* __restrict__ wk, const float* __restrict__ wv,
    const float* __restrict__ bq, const float* __restrict__ bk,
    const float* __restrict__ bv, _Float16* __restrict__ w_h,
    float* __restrict__ bias, _Float16* __restrict__ xt) {
  int bid = blockIdx.x;
  int t = threadIdx.x;
  if (bid < 2048) {
    // ---- transpose role ----
    __shared__ float tile[64][65];
    int nb = bid & 63, cb = (bid >> 6) & 7, b = bid >> 9;
    int c0 = cb * 64, n0 = nb * 64;
    const float* xb = x + (size_t)b * CD * NP;
#pragma unroll
    for (int k = 0; k < 16; k++) {
      int cl = k * 4 + (t >> 6);
      int nl = t & 63;
      tile[cl][nl] = xb[(size_t)(c0 + cl) * NP + n0 + nl];
    }
    __syncthreads();
    _Float16* xtb = xt + ((size_t)b * NP + n0) * CD + c0;
#pragma unroll
    for (int k = 0; k < 2; k++) {
      int nl = k * 32 + (t >> 3);
      int cl = (t & 7) * 8;
      half8 pk;
#pragma unroll
      for (int i = 0; i < 8; i++) pk[i] = (_Float16)tile[cl + i][nl];
      *(half8*)(xtb + (size_t)nl * CD + cl) = pk;
    }
  } else {
    // ---- prep role (128 blocks) ----
    int idx = (bid - 2048) * 256 + t;
    for (int i = idx; i < 640 * 512; i += 128 * 256) {
      int r = i >> 9, c = i & 511;
      float v = (r < 64) ? wq[(r << 9) + c] * LOG2E
              : (r < 128) ? wk[((r - 64) << 9) + c]
                          : wv[((r - 128) << 9) + c];
      w_h[i] = (_Float16)v;
    }
    if (idx < 640) {
      float v = (idx < 64) ? bq[idx] * LOG2E
              : (idx < 128) ? bk[idx - 64]
                            : bv[idx - 128];
      bias[idx] = v;
    }
  }
}

// ---------------------------------------------------------------------------
// Kernel 2: fused QKV projection. V epilogue routed through xls (free after
// the main loop): acc -> LDS (swizzled 16B units) -> 16B coalesced global
// stores (was ~192 scalar 2B stores/wave at 32B coalescing).
// ---------------------------------------------------------------------------
__global__ __launch_bounds__(256, 2) void proj_qkv(
    const _Float16* __restrict__ w_h, const float* __restrict__ bias,
    const _Float16* __restrict__ xt, _Float16* __restrict__ q_h,
    _Float16* __restrict__ k_h, _Float16* __restrict__ v_h) {
  __shared__ _Float16 xls[64 * 512];   // 64 KB, XOR-swizzled 16B units
  int t = threadIdx.x, w = t >> 6, lane = t & 63;
  int col = lane & 15, quad = lane >> 4;
  int rbh = blockIdx.x, nb = blockIdx.y, b = blockIdx.z;
  int n0 = nb * 64;
  const _Float16* xtb = xt + ((size_t)b * NP + n0) * CD;
#pragma unroll
  for (int j = 0; j < 16; j++) {
    int u = t + j * 256;
    int row = u >> 6, un = u & 63;
    *(half8*)(xls + row * 512 + ((un ^ (row & 7)) << 3)) =
        *(const half8*)(xtb + (size_t)row * CD + un * 8);
  }
  __syncthreads();

  int rw = rbh * 320 + w * 80;
  floatx4 acc[5][4] = {};
  for (int c = 0; c < CD; c += 32) {
    int cu = c >> 3;
    half8 a[5], bf[4];
#pragma unroll
    for (int i = 0; i < 5; i++)
      a[i] = *(const half8*)(w_h + (size_t)(rw + i * 16 + col) * CD + c + quad * 8);
#pragma unroll
    for (int j = 0; j < 4; j++) {
      int row = j * 16 + col;
      bf[j] = *(const half8*)(xls + row * 512 + (((cu + quad) ^ (row & 7)) << 3));
    }
#pragma unroll
    for (int i = 0; i < 5; i++)
#pragma unroll
      for (int j = 0; j < 4; j++)
        acc[i][j] = __builtin_amdgcn_mfma_f32_16x16x32_f16(a[i], bf[j], acc[i][j], 0, 0, 0);
  }

  // all waves done reading xls -> safe to reuse it for the V transpose
  __syncthreads();

#pragma unroll
  for (int i = 0; i < 5; i++) {
    int r0 = rw + i * 16;
    float bi[4];
#pragma unroll
    for (int rr = 0; rr < 4; rr++) bi[rr] = bias[r0 + quad * 4 + rr];
    if (r0 < 128) {
      _Float16* dst = (r0 < 64 ? q_h + (size_t)b * NP * MID + r0
                               : k_h + (size_t)b * NP * MID + (r0 - 64));
#pragma unroll
      for (int j = 0; j < 4; j++) {
        int n = n0 + j * 16 + col;
        half4 pk;
#pragma unroll
        for (int rr = 0; rr < 4; rr++) pk[rr] = (_Float16)(acc[i][j][rr] + bi[rr]);
        *(half4*)(dst + (size_t)n * MID + quad * 4) = pk;
      }
    } else {
      // V tile -> xls at [vl][n], 16B-unit swizzle u^(row&7)
      int vl = r0 - (rbh ? 320 : 128) + quad * 4;
#pragma unroll
      for (int j = 0; j < 4; j++) {
#pragma unroll
        for (int rr = 0; rr < 4; rr++) {
          int row = vl + rr;
          int cu2 = j * 2 + (col >> 3);
          xls[row * 64 + ((cu2 ^ (row & 7)) << 3) + (col & 7)] =
              (_Float16)(acc[i][j][rr] + bi[rr]);
        }
      }
    }
  }
  __syncthreads();

  // V read-back: 16B units, 128B-coalesced global stores
  int nrows = rbh ? 320 : 192;
  int grow0 = rbh ? 192 : 0;
  _Float16* vdst = v_h + (size_t)b * CD * NP + n0;
  for (int u = t; u < nrows * 8; u += 256) {
    int row = u >> 3, un = u & 7;
    half8 pk = *(const half8*)(xls + row * 64 + ((un ^ (row & 7)) << 3));
    *(half8*)(vdst + (size_t)(grow0 + row) * NP + un * 8) = pk;
  }
}

// ---------------------------------------------------------------------------
// Kernel 3: row max of S (unchanged).
// ---------------------------------------------------------------------------
__global__ __launch_bounds__(256) void rowmax(const _Float16* __restrict__ q_h,
                                              const _Float16* __restrict__ k_h,
                                              float* __restrict__ M) {
  int qb = blockIdx.x, b = blockIdx.y;
  int t = threadIdx.x, w = t >> 6, lane = t & 63;
  int col = lane & 15, quad = lane >> 4;
  int q0 = qb * 32;
  const _Float16* qp = q_h + ((size_t)b * NP + q0) * MID;
  half8 bq[2][2];
#pragma unroll
  for (int qt = 0; qt < 2; qt++)
#pragma unroll
    for (int h = 0; h < 2; h++)
      bq[qt][h] = *(const half8*)(qp + (size_t)(qt * 16 + col) * MID + h * 32 + quad * 8);
  const _Float16* kp = k_h + ((size_t)b * NP + (size_t)w * 1024) * MID;
  float m[2] = {-1e30f, -1e30f};
#pragma unroll 4
  for (int n = 0; n < 1024; n += 16) {
    half8 ak0 = *(const half8*)(kp + (size_t)(n + col) * MID + quad * 8);
    half8 ak1 = *(const half8*)(kp + (size_t)(n + col) * MID + 32 + quad * 8);
#pragma unroll
    for (int qt = 0; qt < 2; qt++) {
      floatx4 s = {};
      s = __builtin_amdgcn_mfma_f32_16x16x32_f16(ak0, bq[qt][0], s, 0, 0, 0);
      s = __builtin_amdgcn_mfma_f32_16x16x32_f16(ak1, bq[qt][1], s, 0, 0, 0);
      m[qt] = fmaxf(m[qt], fmaxf(fmaxf(s[0], s[1]), fmaxf(s[2], s[3])));
    }
  }
  __shared__ float red[4][2][16];
#pragma unroll
  for (int qt = 0; qt < 2; qt++) {
    m[qt] = fmaxf(m[qt], __shfl_xor(m[qt], 16));
    m[qt] = fmaxf(m[qt], __shfl_xor(m[qt], 32));
  }
  if (quad == 0) {
    red[w][0][col] = m[0];
    red[w][1][col] = m[1];
  }
  __syncthreads();
  if (t < 32) {
    int qt = t >> 4, c = t & 15;
    float mm = fmaxf(fmaxf(red[0][qt][c], red[1][qt][c]),
                     fmaxf(red[2][qt][c], red[3][qt][c]));
    M[(size_t)b * NP + q0 + t] = mm;
  }
}

// ---------------------------------------------------------------------------
// Kernel 4: attention + PV + epilogue, v14 (split vmcnt gates).
// Grid 512 = b(4) x ds(2) x qb(64); block = 4 waves = 64q x 256d.
// vs v13 (102us, MfmaUtil 35.5): the single vmcnt(0) at body top drained
// all 10 DMAs, but score needs only K(ci) -- the 2 OLDEST in flight
// (issue order last body: K(ci) x2 then V(ci-1) x8; vmcnt retires in
// order). v14: top gate = vmcnt(8) (K only); vmcnt(0) for V deferred
// until after the score MFMAs (V gets ~200 more cycles of flight).
// Refill DMAs issue right after the read-drain lgkm(0), BEFORE exp/
// P-write (they only need reads retired) -> ~300 more flight cycles.
// All gates remain order-independent (lgkm(0); in-order vmcnt over
// asm DMAs only -- no compiler VMEM in-loop).
// LDS 58624B: vbuf 2x16K (h-index) | kbuf 8K | pbuf 2x8K | lred/lfin.
// ---------------------------------------------------------------------------
#define DMA16(gp, ldsoff)                                                      \
  asm volatile("s_mov_b32 m0, %0\n\t"                                         \
               "global_load_lds_dwordx4 %1, off"                              \
               :: "s"(__builtin_amdgcn_readfirstlane((int)(ldsoff))),          \
                  "v"(gp)                                                      \
               : "memory")

__global__ __launch_bounds__(256, 2) void attn_pv(
    const _Float16* __restrict__ q_h, const _Float16* __restrict__ k_h,
    const _Float16* __restrict__ v_h, const float* __restrict__ M,
    const float* __restrict__ x, const float* __restrict__ alpha_p,
    float* __restrict__ out) {
  int bid = blockIdx.x;
  int combo = bid & 7;               // -> XCD via round-robin dispatch
  int b = combo >> 1, ds = combo & 1;
  int qb = bid >> 3;                 // 0..63
  int q0 = qb * 64, d0 = ds * 256;

  int t = threadIdx.x, w = t >> 6, lane = t & 63;
  int col = lane & 15, quad = lane >> 4;
  int c7 = col & 7;

  __shared__ floatx4 smem4[58624 / 16];
  char* smem = (char*)smem4;
  char* vbufB = smem;                    // 2 x 16384 (h-indexed)
  char* kbufB = smem + 32768;            // 8192 (single buffer)
  char* pbufB = smem + 40960;            // 2 x 8192 (chunk parity)
  float* lred = (float*)(smem + 57344);  // [4][4][16]
  float* lfin = (float*)(smem + 58368);  // [64]

  const _Float16* qp = q_h + ((size_t)b * NP + q0) * MID;
  half8 bq[4][2];
#pragma unroll
  for (int qt = 0; qt < 4; qt++)
#pragma unroll
    for (int h = 0; h < 2; h++)
      bq[qt][h] = *(const half8*)(qp + (size_t)(qt * 16 + col) * MID + h * 32 + quad * 8);
  float Mq[4];
#pragma unroll
  for (int qt = 0; qt < 4; qt++) Mq[qt] = M[(size_t)b * NP + q0 + qt * 16 + col];

  // DMA source offsets (involution swizzles, constant across chunks)
  int klane = (lane >> 3) * MID + (((lane & 7) ^ ((lane >> 3) & 7)) << 3);
  size_t vlane = (size_t)(lane >> 2) * NP + (((lane & 3) ^ ((lane >> 3) & 3)) << 3);

  const _Float16* kgb = k_h + (size_t)b * NP * MID;
  const _Float16* vgb = v_h + (size_t)(b * CD + d0 + w * 64) * NP;

  floatx4 acc[4][4] = {};            // [dt][qt] = 64 VGPRs, static indices
  float lp[4] = {0.f, 0.f, 0.f, 0.f};

  int kdw = 32768 + w * 2048;        // kbuf wave base (LDS bytes)
  int vdw = w * 4096;                // vbuf wave base

  // read byte-offsets
  int koff0 = col * 128 + ((quad ^ c7) << 4);
  int koff1 = col * 128 + (((quad ^ c7) ^ 4) << 4);
  int vswz = (quad ^ ((col >> 1) & 3)) << 4;
  int pws = ((((quad >> 1) ^ ((col >> 2) & 1)) << 4)) + ((quad & 1) << 3);
  int prs = (((quad & 1) ^ ((col >> 2) & 1)) << 4);

  // ---- prologue: K(0) only ----
#pragma unroll
  for (int j = 0; j < 2; j++)
    DMA16(kgb + (size_t)(w * 16 + j * 8) * MID + klane, kdw + j * 1024);
  asm volatile("s_waitcnt vmcnt(0)" ::: "memory");   // K(0) landed

  // ---- peeled chunk 0: score only; then K(1)+V(0) DMAs ----
  {
    const char* kb = kbufB + w * 2048;
    half8 ak0 = *(const half8*)(kb + koff0);
    half8 ak1 = *(const half8*)(kb + koff1);
    char* pbW = pbufB + w * 2048;                    // pbuf[0]
#pragma unroll
    for (int qt = 0; qt < 4; qt++) {
      floatx4 s = {};
      s = __builtin_amdgcn_mfma_f32_16x16x32_f16(ak0, bq[qt][0], s, 0, 0, 0);
      s = __builtin_amdgcn_mfma_f32_16x16x32_f16(ak1, bq[qt][1], s, 0, 0, 0);
      half4 pk;
#pragma unroll
      for (int r = 0; r < 4; r++) {
        float pv = __builtin_amdgcn_exp2f(s[r] - Mq[qt]);
        lp[qt] += pv;
        pk[r] = (_Float16)pv;
      }
      *(half4*)(pbW + (qt * 16 + col) * 32 + pws) = pk;
    }
    asm volatile("s_waitcnt lgkmcnt(0)" ::: "memory");  // reads+writes drained
    // K(1) FIRST (so it is the oldest pair in flight), then V(0)
#pragma unroll
    for (int j = 0; j < 2; j++)
      DMA16(kgb + (size_t)(64 + w * 16 + j * 8) * MID + klane, kdw + j * 1024);
#pragma unroll
    for (int h = 0; h < 2; h++)
#pragma unroll
      for (int j = 0; j < 4; j++)
        DMA16(vgb + (size_t)(j * 16) * NP + h * 32 + vlane,
              h * 16384 + vdw + j * 1024);
    asm volatile("s_barrier" ::: "memory");          // P(0) published
  }

  // ---- main loop: body ci does score(ci) + PV(ci-1) ----
  for (int ci = 1; ci < 64; ci++) {
    int p = ci & 1;
    int nc = ci * 64;
    int nxt = ((ci + 1) & 63) * 64;

    // K(ci) = oldest 2 in flight -> vmcnt(8) retires exactly them
    asm volatile("s_waitcnt vmcnt(8)" ::: "memory");

    const char* kb = kbufB + w * 2048;
    half8 ak0 = *(const half8*)(kb + koff0);
    half8 ak1 = *(const half8*)(kb + koff1);
    const char* pbR = pbufB + (1 - p) * 8192;   // P(ci-1)
    half8 bp[2][4];
#pragma unroll
    for (int h = 0; h < 2; h++)
#pragma unroll
      for (int qt = 0; qt < 4; qt++)
        bp[h][qt] = *(const half8*)(pbR + (2 * h + (quad >> 1)) * 2048 +
                                    (qt * 16 + col) * 32 + prs);

    // score(ci)
    floatx4 s[4];
#pragma unroll
    for (int qt = 0; qt < 4; qt++) {
      floatx4 z = {};
      z = __builtin_amdgcn_mfma_f32_16x16x32_f16(ak0, bq[qt][0], z, 0, 0, 0);
      z = __builtin_amdgcn_mfma_f32_16x16x32_f16(ak1, bq[qt][1], z, 0, 0, 0);
      s[qt] = z;
    }

    // V(ci-1) landed (it had score-phase extra flight)
    asm volatile("s_waitcnt vmcnt(0)" ::: "memory");
    half8 av[2][4];
#pragma unroll
    for (int h = 0; h < 2; h++)
#pragma unroll
      for (int dt = 0; dt < 4; dt++)
        av[h][dt] = *(const half8*)(vbufB + h * 16384 + vdw + dt * 1024 +
                                    col * 64 + vswz);

    // ALL reads retired (order-independent) -> bufs reusable; refill NOW
    // (before exp/P-write: DMAs only need reads drained) K first, then V.
    asm volatile("s_waitcnt lgkmcnt(0)" ::: "memory");
#pragma unroll
    for (int j = 0; j < 2; j++)
      DMA16(kgb + (size_t)(nxt + w * 16 + j * 8) * MID + klane, kdw + j * 1024);
#pragma unroll
    for (int h = 0; h < 2; h++)
#pragma unroll
      for (int j = 0; j < 4; j++)
        DMA16(vgb + (size_t)(j * 16) * NP + nc + h * 32 + vlane,
              h * 16384 + vdw + j * 1024);

    // exp + P-write(ci) -> pbuf[p] (not a DMA target; safe after refills)
    char* pbW = pbufB + p * 8192 + w * 2048;
#pragma unroll
    for (int qt = 0; qt < 4; qt++) {
      half4 pk;
#pragma unroll
      for (int r = 0; r < 4; r++) {
        float pv = __builtin_amdgcn_exp2f(s[qt][r] - Mq[qt]);
        lp[qt] += pv;
        pk[r] = (_Float16)pv;
      }
      *(half4*)(pbW + (qt * 16 + col) * 32 + pws) = pk;
    }

    // PV(ci-1): dense 32-MFMA cluster, operands all in regs; DMAs fly over
    __builtin_amdgcn_s_setprio(1);
#pragma unroll
    for (int h = 0; h < 2; h++)
#pragma unroll
      for (int dt = 0; dt < 4; dt++)
#pragma unroll
        for (int qt = 0; qt < 4; qt++)
          acc[dt][qt] = __builtin_amdgcn_mfma_f32_16x16x32_f16(
              av[h][dt], bp[h][qt], acc[dt][qt], 0, 0, 0);
    __builtin_amdgcn_s_setprio(0);

    // ONE barrier per chunk: P(ci) published (drains the 4 P-writes)
    asm volatile("s_waitcnt lgkmcnt(0)\n\ts_barrier" ::: "memory");
  }

  // ---- epilogue: PV(63) ----
  asm volatile("s_waitcnt vmcnt(0)" ::: "memory");   // V(63) landed
  {
    const char* pbR = pbufB + 8192;                  // pbuf[1] = P(63)
    half8 bp[2][4];
#pragma unroll
    for (int h = 0; h < 2; h++)
#pragma unroll
      for (int qt = 0; qt < 4; qt++)
        bp[h][qt] = *(const half8*)(pbR + (2 * h + (quad >> 1)) * 2048 +
                                    (qt * 16 + col) * 32 + prs);
    half8 av[2][4];
#pragma unroll
    for (int h = 0; h < 2; h++)
#pragma unroll
      for (int dt = 0; dt < 4; dt++)
        av[h][dt] = *(const half8*)(vbufB + h * 16384 + vdw + dt * 1024 +
                                    col * 64 + vswz);
#pragma unroll
    for (int h = 0; h < 2; h++)
#pragma unroll
      for (int dt = 0; dt < 4; dt++)
#pragma unroll
        for (int qt = 0; qt < 4; qt++)
          acc[dt][qt] = __builtin_amdgcn_mfma_f32_16x16x32_f16(
              av[h][dt], bp[h][qt], acc[dt][qt], 0, 0, 0);
  }

  // l: lane's partial covers its quad's 4 keys of this wave's sections
#pragma unroll
  for (int qt = 0; qt < 4; qt++) {
    lp[qt] += __shfl_xor(lp[qt], 16);
    lp[qt] += __shfl_xor(lp[qt], 32);
    if (quad == 0) lred[(w * 4 + qt) * 16 + col] = lp[qt];
  }
  __syncthreads();
  if (t < 64) {
    int qt = t >> 4, c = t & 15;
    float l = lred[(0 + qt) * 16 + c] + lred[(4 + qt) * 16 + c] +
              lred[(8 + qt) * 16 + c] + lred[(12 + qt) * 16 + c];
    lfin[t] = alpha_p[0] / l;
  }
  __syncthreads();

  // epilogue: fused alpha/l scale + residual; 64B-segment coalesced stores
  const float* xp = x + ((size_t)(b * CD + d0) + w * 64) * NP;
  float* op = out + ((size_t)(b * CD + d0) + w * 64) * NP;
#pragma unroll
  for (int dt = 0; dt < 4; dt++)
#pragma unroll
    for (int qt = 0; qt < 4; qt++) {
      float linv = lfin[qt * 16 + col];
#pragma unroll
      for (int r = 0; r < 4; r++) {
        size_t o = (size_t)(dt * 16 + quad * 4 + r) * NP + q0 + qt * 16 + col;
        op[o] = acc[dt][qt][r] * linv + xp[o];
      }
    }
}

// ---------------------------------------------------------------------------
extern "C" void kernel_launch(void* const* d_in, const int* in_sizes, int n_in,
                              void* d_out, int out_size, void* d_ws, size_t ws_size,
                              hipStream_t stream) {
  const float* x     = (const float*)d_in[0];
  const float* wq    = (const float*)d_in[1];
  const float* bq    = (const float*)d_in[2];
  const float* wk    = (const float*)d_in[3];
  const float* bk    = (const float*)d_in[4];
  const float* wv    = (const float*)d_in[5];
  const float* bv    = (const float*)d_in[6];
  const float* alpha = (const float*)d_in[7];
  float* out = (float*)d_out;

  char* ws = (char*)d_ws;
  _Float16* w_h  = (_Float16*)(ws);                    // 640*512*2   = 655360
  float*    bias = (float*)(ws + 655360);              // 640*4       = 2560
  float*    Mbuf = (float*)(ws + 657920);              // 4*4096*4    = 65536
  _Float16* xt   = (_Float16*)(ws + 723456);           // 4*4096*512*2= 16777216
  _Float16* q_h  = (_Float16*)(ws + 17500672);         // 4*4096*64*2 = 2097152
  _Float16* k_h  = (_Float16*)(ws + 19597824);         // 4*4096*64*2 = 2097152
  _Float16* v_h  = (_Float16*)(ws + 21694976);         // 4*512*4096*2= 16777216

  prep_trans<<<2176, 256, 0, stream>>>(x, wq, wk, wv, bq, bk, bv, w_h, bias, xt);
  proj_qkv<<<dim3(2, 64, BB), 256, 0, stream>>>(w_h, bias, xt, q_h, k_h, v_h);
  rowmax<<<dim3(128, BB), 256, 0, stream>>>(q_h, k_h, Mbuf);
  attn_pv<<<512, 256, 0, stream>>>(q_h, k_h, v_h, Mbuf, x, alpha, out);
}